// Round 21
// baseline (13043.091 us; speedup 1.0000x reference)
//
#include <hip/hip_runtime.h>
#include <cstdint>

#define NB 128   // batch
#define NS 1024  // seq len
#define NV 128   // input dim
#define NH 256   // hidden
#define CH 64    // chunk length
#define NCH (NS / CH)

typedef _Float16 f16;
typedef _Float16 h2 __attribute__((ext_vector_type(2)));
typedef _Float16 f16x8 __attribute__((ext_vector_type(8)));
typedef float f32x4 __attribute__((ext_vector_type(4)));
typedef uint32_t u32;

static __device__ __forceinline__ float fdot2(u32 a, u32 b, float c) {
  return __builtin_amdgcn_fdot2(__builtin_bit_cast(h2, a),
                                __builtin_bit_cast(h2, b), c, false);
}
static __device__ __forceinline__ u32 pkh(float a, float b) {  // RTN
  union { h2 h; u32 u; } cv; cv.h = h2{(f16)a, (f16)b}; return cv.u;
}
static __device__ __forceinline__ u32 pkz(float a, float b) {  // RTZ (x only)
  return __builtin_bit_cast(u32, __builtin_amdgcn_cvt_pkrtz(a, b));
}
static __device__ __forceinline__ float sigm(float x) { return 1.f / (1.f + __expf(-x)); }
static __device__ __forceinline__ float tanh_(float x) { return 1.f - 2.f / (__expf(2.f * x) + 1.f); }

// AGPR pin: legal here because the ONLY consumer is MFMA, which reads AGPR
// operands natively (ISA §10) — no accvgpr_read copies (unlike r13's v_dot).
static __device__ __forceinline__ void pin4a(uint4& v) {
  asm volatile("" : "+a"(v.x), "+a"(v.y), "+a"(v.z), "+a"(v.w));
}

// ---------------------------------------------------------------------------
// prepack: four weight matrices f32 -> packed f16 pairs, once per call.
// ---------------------------------------------------------------------------
__global__ __launch_bounds__(1024) void prepack_kernel(
    const float* __restrict__ Wih0, const float* __restrict__ Wih1,
    const float* __restrict__ Whh0, const float* __restrict__ Whh1,
    u32* __restrict__ Wih0p, u32* __restrict__ Wih1p,
    u32* __restrict__ Whh0p, u32* __restrict__ Whh1p) {
  const int g = blockIdx.x * 1024 + threadIdx.x;
  const float* src; u32* dst; int off;
  if (g < 65536)       { src = Wih0; dst = Wih0p; off = g; }
  else if (g < 196608) { src = Wih1; dst = Wih1p; off = g - 65536; }
  else if (g < 327680) { src = Whh0; dst = Whh0p; off = g - 196608; }
  else                 { src = Whh1; dst = Whh1p; off = g - 327680; }
  dst[off] = pkh(src[2 * off], src[2 * off + 1]);
}

// ---------------------------------------------------------------------------
// gemm pair, MFMA version — byte-identical to r18/r19/r20 (out of top-5).
// ---------------------------------------------------------------------------
#define P1S 132
#define P0S 68
__global__ __launch_bounds__(512) void gemm_pair_kernel(
    const u32* __restrict__ g1_in, const u32* __restrict__ g1_Wp,
    const float* __restrict__ g1_bih, const float* __restrict__ g1_bhh,
    f16* __restrict__ g1_xg, int g1_t0, int g1_on,
    const float* __restrict__ g0_x, const u32* __restrict__ g0_Wp,
    const float* __restrict__ g0_bih, const float* __restrict__ g0_bhh,
    f16* __restrict__ g0_xg, int g0_t0, int g0_on) {
  __shared__ __align__(16) u32 panel[64 * P1S];
  const int tid = threadIdx.x;
  const int blk = blockIdx.x;
  const int lane = tid & 63;
  const int w = tid >> 6;
  const int lrow = lane & 15;
  const int lk = lane >> 4;

  if (blk < 128) {
    if (!g1_on) return;
    const int b = blk;
    {
      const uint4* src = (const uint4*)(g1_in + ((size_t)b * NS + g1_t0) * 128);
      const int t = tid >> 3, cc = tid & 7;
#pragma unroll
      for (int q = 0; q < 4; ++q) {
        uint4 v = src[t * 32 + cc * 4 + q];
        *(uint4*)&panel[t * P1S + cc * 16 + q * 4] = v;
      }
    }
    float bs[8];
#pragma unroll
    for (int n = 0; n < 8; ++n) {
      const int r = w * 128 + n * 16 + lrow;
      bs[n] = g1_bih[r] + g1_bhh[r];
    }
    __syncthreads();
    f32x4 acc[4][8] = {};
#pragma unroll 1
    for (int kc = 0; kc < 8; ++kc) {
      uint4 af[4];
#pragma unroll
      for (int m = 0; m < 4; ++m)
        af[m] = *(const uint4*)&panel[(m * 16 + lrow) * P1S + kc * 16 + lk * 4];
#pragma unroll
      for (int n = 0; n < 8; ++n) {
        const int r = w * 128 + n * 16 + lrow;
        uint4 bf = *(const uint4*)(g1_Wp + (size_t)r * 128 + kc * 16 + lk * 4);
#pragma unroll
        for (int m = 0; m < 4; ++m)
          acc[m][n] = __builtin_amdgcn_mfma_f32_16x16x32_f16(
              __builtin_bit_cast(f16x8, af[m]), __builtin_bit_cast(f16x8, bf),
              acc[m][n], 0, 0, 0);
      }
    }
#pragma unroll
    for (int m = 0; m < 4; ++m)
#pragma unroll
      for (int n = 0; n < 8; ++n) {
        const int r = w * 128 + n * 16 + lrow;
#pragma unroll
        for (int j = 0; j < 4; ++j) {
          const int t = m * 16 + lk * 4 + j;
          g1_xg[((size_t)b * CH + t) * 1024 + r] = (f16)(acc[m][n][j] + bs[n]);
        }
      }
  } else {
    if (!g0_on) return;
    const int b = blk - 128;
    {
      const float4* src = (const float4*)(g0_x + ((size_t)b * NS + g0_t0) * NV);
      const int t = tid >> 3, cc = tid & 7;
      float4 v0 = src[t * 32 + cc * 4 + 0];
      float4 v1 = src[t * 32 + cc * 4 + 1];
      float4 v2 = src[t * 32 + cc * 4 + 2];
      float4 v3 = src[t * 32 + cc * 4 + 3];
      *(uint4*)&panel[t * P0S + cc * 8 + 0] =
          uint4{pkz(v0.x, v0.y), pkz(v0.z, v0.w), pkz(v1.x, v1.y), pkz(v1.z, v1.w)};
      *(uint4*)&panel[t * P0S + cc * 8 + 4] =
          uint4{pkz(v2.x, v2.y), pkz(v2.z, v2.w), pkz(v3.x, v3.y), pkz(v3.z, v3.w)};
    }
    float bs[8];
#pragma unroll
    for (int n = 0; n < 8; ++n) {
      const int r = w * 128 + n * 16 + lrow;
      bs[n] = g0_bih[r] + g0_bhh[r];
    }
    __syncthreads();
    f32x4 acc[4][8] = {};
#pragma unroll 1
    for (int kc = 0; kc < 4; ++kc) {
      uint4 af[4];
#pragma unroll
      for (int m = 0; m < 4; ++m)
        af[m] = *(const uint4*)&panel[(m * 16 + lrow) * P0S + kc * 16 + lk * 4];
#pragma unroll
      for (int n = 0; n < 8; ++n) {
        const int r = w * 128 + n * 16 + lrow;
        uint4 bf = *(const uint4*)(g0_Wp + (size_t)r * 64 + kc * 16 + lk * 4);
#pragma unroll
        for (int m = 0; m < 4; ++m)
          acc[m][n] = __builtin_amdgcn_mfma_f32_16x16x32_f16(
              __builtin_bit_cast(f16x8, af[m]), __builtin_bit_cast(f16x8, bf),
              acc[m][n], 0, 0, 0);
      }
    }
#pragma unroll
    for (int m = 0; m < 4; ++m)
#pragma unroll
      for (int n = 0; n < 8; ++n) {
        const int r = w * 128 + n * 16 + lrow;
#pragma unroll
        for (int j = 0; j < 4; ++j) {
          const int t = m * 16 + lk * 4 + j;
          g0_xg[((size_t)b * CH + t) * 1024 + r] = (f16)(acc[m][n][j] + bs[n]);
        }
      }
  }
}

// ---------------------------------------------------------------------------
// scan pair — MFMA RECURRENCE. One WG = 16 batches (bg). Per step:
// H(t-1)[16x256] x Whh^T[256x1024] via 64 mfma_f32_16x16x32_f16 per wave.
// B-frags (64 uint4 = 256 regs) pinned in AGPRs, consumed natively by MFMA.
// Wave w owns n-tiles {g*16 + w, g*16 + w+8} for all gates g -> gate combine
// is fully lane-local: lane holds (m = lk*4+j, u = (w|w+8)*16 + lrow) for all
// 4 gates in 4 acc tiles. c-state in regs. xg tile staged to LDS per step
// (conflict-free strides); ONE barrier per step; h(t-1) global store issued
// at next step's top so its vmcnt drain hides under the step.
// grid 16: blocks [0,8)=role A (scan1 s), [8,16)=role B (scan0 s+1).
// Fragment conventions identical to the r18-verified gemm.
// ---------------------------------------------------------------------------
#define HLS 132   // hL row stride (u32)
#define XGS 1032  // xgs row stride (f16): 16B-aligned, 2-way-max on u16 reads
__global__ __attribute__((amdgpu_flat_work_group_size(512, 512),
                          amdgpu_waves_per_eu(2, 2)))
void scan_pair_kernel(
    const f16* __restrict__ xgA, const u32* __restrict__ WhhAp,
    u32* __restrict__ slotsA, u32* __restrict__ hseedA, float* __restrict__ carryA,
    int t0A, int firstA, int onA,
    const f16* __restrict__ xgB, const u32* __restrict__ WhhBp,
    u32* __restrict__ slotsB, u32* __restrict__ hseedB, float* __restrict__ carryB,
    int t0B, int firstB, int onB) {
  __shared__ __align__(16) u32 hL[2][16 * HLS];    // 16.9 KiB: h as [m][128 u32]
  __shared__ __align__(16) f16 xgs[2][16 * XGS];   // 66 KiB: xg tile [m][1024]
  const int blk = blockIdx.x;
  const int tid = threadIdx.x;
  const f16* xg; const u32* Wp; u32* slots; u32* hseed; float* carry;
  int t0, first, bg;
  if (blk < 8) {
    if (!onA) return;
    bg = blk; xg = xgA; Wp = WhhAp; slots = slotsA; hseed = hseedA; carry = carryA;
    t0 = t0A; first = firstA;
  } else {
    if (!onB) return;
    bg = blk - 8; xg = xgB; Wp = WhhBp; slots = slotsB; hseed = hseedB; carry = carryB;
    t0 = t0B; first = firstB;
  }
  const int lane = tid & 63;
  const int w = tid >> 6;        // wave 0..7
  const int lrow = lane & 15;
  const int lk = lane >> 4;
  const int m_ = tid >> 5;       // staging row 0..15
  const int c4 = tid & 31;       // staging col group

  // B-fragments [s(2)][g(4)][kc(8)]: r18-verified indexing; AGPR-resident.
  uint4 wB[64];
#pragma unroll
  for (int s = 0; s < 2; ++s)
#pragma unroll
    for (int g = 0; g < 4; ++g) {
      const int r = g * 256 + (w + 8 * s) * 16 + lrow;
      const u32* pr = Wp + (size_t)r * 128 + lk * 4;
#pragma unroll
      for (int kc = 0; kc < 8; ++kc)
        wB[(s * 4 + g) * 8 + kc] = *(const uint4*)(pr + kc * 16);
    }
#pragma unroll
  for (int k = 0; k < 64; ++k) pin4a(wB[k]);

  // seed hL[0]; stage xg tile 0 into xgs[0]
  if (first) {
    *(uint4*)&hL[0][m_ * HLS + c4 * 4] = uint4{0u, 0u, 0u, 0u};
  } else {
    *(uint4*)&hL[0][m_ * HLS + c4 * 4] =
        *(const uint4*)(hseed + (size_t)(bg * 16 + m_) * 128 + c4 * 4);
  }
  {
    const f16* sp = xg + ((size_t)(bg * 16 + m_) * CH + 0) * 1024 + c4 * 32;
    f16* dp = &xgs[0][m_ * XGS + c4 * 32];
    *(uint4*)(dp + 0)  = *(const uint4*)(sp + 0);
    *(uint4*)(dp + 8)  = *(const uint4*)(sp + 8);
    *(uint4*)(dp + 16) = *(const uint4*)(sp + 16);
    *(uint4*)(dp + 24) = *(const uint4*)(sp + 24);
  }
  float cst[2][4], hpv[2][4];
  if (first) {
#pragma unroll
    for (int s = 0; s < 2; ++s)
#pragma unroll
      for (int j = 0; j < 4; ++j) cst[s][j] = 0.f;
  } else {
#pragma unroll
    for (int s = 0; s < 2; ++s) {
      const int u = (w + 8 * s) * 16 + lrow;
#pragma unroll
      for (int j = 0; j < 4; ++j)
        cst[s][j] = carry[(size_t)(bg * 16 + lk * 4 + j) * 256 + u];
    }
  }
  __syncthreads();

#pragma unroll 1
  for (int tl = 0; tl < CH; ++tl) {
    const int cur = tl & 1, nxt = cur ^ 1;
    // 1. global-store h(tl-1) (issued early; drain hides under this step)
    if (tl > 0) {
#pragma unroll
      for (int s = 0; s < 2; ++s) {
        const int u = (w + 8 * s) * 16 + lrow;
#pragma unroll
        for (int j = 0; j < 4; ++j)
          ((f16*)slots)[((size_t)(bg * 16 + lk * 4 + j) * NS + (t0 + tl - 1)) * 256 + u] =
              (f16)hpv[s][j];
      }
    }
    // 2. prefetch xg tile tl+1 (global -> regs)
    uint4 pf0, pf1, pf2, pf3;
    {
      const int tn = (tl + 1 < CH) ? tl + 1 : tl;
      const f16* sp = xg + ((size_t)(bg * 16 + m_) * CH + tn) * 1024 + c4 * 32;
      pf0 = *(const uint4*)(sp + 0);
      pf1 = *(const uint4*)(sp + 8);
      pf2 = *(const uint4*)(sp + 16);
      pf3 = *(const uint4*)(sp + 24);
    }
    // 3. A-fragments from hL[cur] (row = batch = lrow; r18-verified indexing)
    uint4 af[8];
#pragma unroll
    for (int kc = 0; kc < 8; ++kc)
      af[kc] = *(const uint4*)&hL[cur][lrow * HLS + kc * 16 + lk * 4];
    // 4. 64 MFMAs (B from AGPRs)
    f32x4 acc[8] = {};
#pragma unroll
    for (int kc = 0; kc < 8; ++kc)
#pragma unroll
      for (int q = 0; q < 8; ++q)
        acc[q] = __builtin_amdgcn_mfma_f32_16x16x32_f16(
            __builtin_bit_cast(f16x8, af[kc]), __builtin_bit_cast(f16x8, wB[q * 8 + kc]),
            acc[q], 0, 0, 0);
    // 5. gates (fully lane-local)
#pragma unroll
    for (int s = 0; s < 2; ++s) {
      const int ub = (w + 8 * s) * 16 + lrow;
#pragma unroll
      for (int j = 0; j < 4; ++j) {
        const int m = lk * 4 + j;
        const float xi = (float)xgs[cur][m * XGS + 0   + ub];
        const float xf = (float)xgs[cur][m * XGS + 256 + ub];
        const float xc = (float)xgs[cur][m * XGS + 512 + ub];
        const float xo = (float)xgs[cur][m * XGS + 768 + ub];
        const float gi = sigm(acc[s * 4 + 0][j] + xi);
        const float gf = sigm(acc[s * 4 + 1][j] + xf);
        const float gg = tanh_(acc[s * 4 + 2][j] + xc);
        const float go = sigm(acc[s * 4 + 3][j] + xo);
        cst[s][j] = gf * cst[s][j] + gi * gg;
        const float h = go * tanh_(cst[s][j]);
        hpv[s][j] = h;
        ((f16*)&hL[nxt][0])[m * (HLS * 2) + ub] = (f16)h;
      }
    }
    // 6. write prefetched xg tile to xgs[nxt]
    {
      f16* dp = &xgs[nxt][m_ * XGS + c4 * 32];
      *(uint4*)(dp + 0)  = pf0;
      *(uint4*)(dp + 8)  = pf1;
      *(uint4*)(dp + 16) = pf2;
      *(uint4*)(dp + 24) = pf3;
    }
    __syncthreads();
  }
  // epilogue: final h store + carries
#pragma unroll
  for (int s = 0; s < 2; ++s) {
    const int u = (w + 8 * s) * 16 + lrow;
#pragma unroll
    for (int j = 0; j < 4; ++j) {
      ((f16*)slots)[((size_t)(bg * 16 + lk * 4 + j) * NS + (t0 + CH - 1)) * 256 + u] =
          (f16)hpv[s][j];
      carry[(size_t)(bg * 16 + lk * 4 + j) * 256 + u] = cst[s][j];
    }
  }
  // hseed from hL[0] (CH even -> final h lives in hL[0])
  *(uint4*)(hseed + (size_t)(bg * 16 + m_) * 128 + c4 * 4) =
      *(const uint4*)&hL[0][m_ * HLS + c4 * 4];
}

// ---------------------------------------------------------------------------
// outproj: out = Wout·h1 + b, IN PLACE over d_out slots. Unchanged (r11).
// ---------------------------------------------------------------------------
#define OPS 140
static __device__ __forceinline__ int swzc(int col) { return col + 4 * (col >> 5); }

__global__ __launch_bounds__(1024) void outproj_kernel(
    const float* __restrict__ Wout, const float* __restrict__ bout,
    u32* __restrict__ io) {
  const int bs = blockIdx.x;  // 2048 blocks
  const int b = bs >> 4;
  const int t0 = (bs & 15) * 64;
  const int tid = threadIdx.x;
  const int p = tid & 7;
  const int vq = tid >> 3;

  __shared__ u32 h1L[64 * OPS];
  __shared__ float outL[64 * OPS];

  const u32* src = io + ((size_t)b * NS + t0) * 128;
  uint4 s0 = *(const uint4*)(src + (size_t)tid * 8);
  uint4 s1 = *(const uint4*)(src + (size_t)tid * 8 + 4);

  u32 wo[16];
  const float* pw = Wout + (size_t)vq * NH + p * 32;
#pragma unroll
  for (int k = 0; k < 8; ++k) {
    float4 w4 = *(const float4*)(pw + 4 * k);
    wo[2 * k] = pkh(w4.x, w4.y); wo[2 * k + 1] = pkh(w4.z, w4.w);
  }
  const float bo = bout[vq];

  {
    const int sr = tid >> 4;
    const int sc = (tid & 15) * 8;
    const int base = sr * OPS + swzc(sc);
    *(uint4*)&h1L[base] = s0;
    *(uint4*)&h1L[base + 4] = s1;
  }
  __syncthreads();

#pragma unroll 4
  for (int s = 0; s < 64; ++s) {
    float oa = 0.f;
#pragma unroll
    for (int q = 0; q < 4; ++q) {
      uint4 hq = *(const uint4*)&h1L[s * OPS + swzc(p * 16 + 4 * q)];
      u32 hw[4] = {hq.x, hq.y, hq.z, hq.w};
#pragma unroll
      for (int j = 0; j < 4; ++j) oa = fdot2(wo[4 * q + j], hw[j], oa);
    }
    oa += __shfl_xor(oa, 1);
    oa += __shfl_xor(oa, 2);
    oa += __shfl_xor(oa, 4);
    if (p == 0) outL[s * OPS + swzc(vq)] = oa + bo;
  }
  __syncthreads();

  float* df = (float*)(io + ((size_t)b * NS + t0) * 128);
  {
    const int sr = tid >> 4;
    const int sc = (tid & 15) * 8;
    const int base = sr * OPS + swzc(sc);
    *(float4*)(df + (size_t)tid * 8) = *(float4*)&outL[base];
    *(float4*)(df + (size_t)tid * 8 + 4) = *(float4*)&outL[base + 4];
  }
}

extern "C" void kernel_launch(void* const* d_in, const int* in_sizes, int n_in,
                              void* d_out, int out_size, void* d_ws, size_t ws_size,
                              hipStream_t stream) {
  const float* x    = (const float*)d_in[0];
  const float* Wih0 = (const float*)d_in[1];
  const float* Whh0 = (const float*)d_in[2];
  const float* bih0 = (const float*)d_in[3];
  const float* bhh0 = (const float*)d_in[4];
  const float* Wih1 = (const float*)d_in[5];
  const float* Whh1 = (const float*)d_in[6];
  const float* bih1 = (const float*)d_in[7];
  const float* bhh1 = (const float*)d_in[8];
  const float* Wout = (const float*)d_in[9];
  const float* bout = (const float*)d_in[10];

  // ws (< 38 MiB): xg0 | xg1 | hseed/carry | packed weights
  f16* xg0 = (f16*)d_ws;
  f16* xg1 = (f16*)((char*)d_ws + (16u << 20));
  u32* hseed0 = (u32*)((char*)d_ws + (32u << 20));
  u32* hseed1 = (u32*)((char*)d_ws + (32u << 20) + (64u << 10));
  float* carry0 = (float*)((char*)d_ws + (32u << 20) + (128u << 10));
  float* carry1 = (float*)((char*)d_ws + (32u << 20) + (256u << 10));
  u32* Wih0p = (u32*)((char*)d_ws + (34u << 20));
  u32* Wih1p = (u32*)((char*)d_ws + (35u << 20));
  u32* Whh0p = (u32*)((char*)d_ws + (36u << 20));
  u32* Whh1p = (u32*)((char*)d_ws + (37u << 20));
  u32* slots = (u32*)d_out;  // h0 -> h1 -> f32 out, in place per chunk row

  prepack_kernel<<<448, 1024, 0, stream>>>(Wih0, Wih1, Whh0, Whh1,
                                           Wih0p, Wih1p, Whh0p, Whh1p);

  // prologue: gemm0(0); scan0(0)
  gemm_pair_kernel<<<256, 512, 0, stream>>>(
      nullptr, nullptr, nullptr, nullptr, nullptr, 0, 0,
      x, Wih0p, bih0, bhh0, xg0, 0, 1);
  scan_pair_kernel<<<16, 512, 0, stream>>>(
      nullptr, nullptr, nullptr, nullptr, nullptr, 0, 0, 0,
      xg0, Whh0p, slots, hseed0, carry0, 0, 1, 1);

  // pipeline: {gemm1(s) || gemm0(s+1)}; then {scan1(s) || scan0(s+1)}
  for (int s = 0; s < NCH; ++s) {
    const int g0on = (s + 1 < NCH);
    gemm_pair_kernel<<<256, 512, 0, stream>>>(
        slots, Wih1p, bih1, bhh1, xg1, s * CH, 1,
        x, Wih0p, bih0, bhh0, xg0, (s + 1) * CH, g0on);
    scan_pair_kernel<<<16, 512, 0, stream>>>(
        xg1, Whh1p, slots, hseed1, carry1, s * CH, (s == 0) ? 1 : 0, 1,
        xg0, Whh0p, slots, hseed0, carry0, (s + 1) * CH, 0, g0on);
  }
  outproj_kernel<<<2048, 1024, 0, stream>>>(Wout, bout, slots);
}

// Round 22
// 3318.871 us; speedup vs baseline: 3.9300x; 3.9300x over previous
//
#include <hip/hip_runtime.h>
#include <cstdint>

#define NB 128   // batch
#define NS 1024  // seq len
#define NV 128   // input dim
#define NH 256   // hidden
#define CH 64    // chunk length
#define NCH (NS / CH)

typedef _Float16 f16;
typedef _Float16 h2 __attribute__((ext_vector_type(2)));
typedef _Float16 f16x8 __attribute__((ext_vector_type(8)));
typedef float f32x4 __attribute__((ext_vector_type(4)));
typedef uint32_t u32;

static __device__ __forceinline__ float fdot2(u32 a, u32 b, float c) {
  return __builtin_amdgcn_fdot2(__builtin_bit_cast(h2, a),
                                __builtin_bit_cast(h2, b), c, false);
}
static __device__ __forceinline__ u32 pkh(float a, float b) {  // RTN
  union { h2 h; u32 u; } cv; cv.h = h2{(f16)a, (f16)b}; return cv.u;
}
static __device__ __forceinline__ u32 pkz(float a, float b) {  // RTZ (x only)
  return __builtin_bit_cast(u32, __builtin_amdgcn_cvt_pkrtz(a, b));
}
static __device__ __forceinline__ float sigm(float x) { return 1.f / (1.f + __expf(-x)); }
static __device__ __forceinline__ float tanh_(float x) { return 1.f - 2.f / (__expf(2.f * x) + 1.f); }

static __device__ __forceinline__ void pin4v(uint4& v) {
  asm volatile("" : "+v"(v.x), "+v"(v.y), "+v"(v.z), "+v"(v.w));
}

// ---------------------------------------------------------------------------
// prepack: four weight matrices f32 -> packed f16 pairs, once per call.
// ---------------------------------------------------------------------------
__global__ __launch_bounds__(1024) void prepack_kernel(
    const float* __restrict__ Wih0, const float* __restrict__ Wih1,
    const float* __restrict__ Whh0, const float* __restrict__ Whh1,
    u32* __restrict__ Wih0p, u32* __restrict__ Wih1p,
    u32* __restrict__ Whh0p, u32* __restrict__ Whh1p) {
  const int g = blockIdx.x * 1024 + threadIdx.x;
  const float* src; u32* dst; int off;
  if (g < 65536)       { src = Wih0; dst = Wih0p; off = g; }
  else if (g < 196608) { src = Wih1; dst = Wih1p; off = g - 65536; }
  else if (g < 327680) { src = Whh0; dst = Whh0p; off = g - 196608; }
  else                 { src = Whh1; dst = Whh1p; off = g - 327680; }
  dst[off] = pkh(src[2 * off], src[2 * off + 1]);
}

// ---------------------------------------------------------------------------
// gemm pair, MFMA version — byte-identical to r18/r19/r20 (out of top-5).
// ---------------------------------------------------------------------------
#define P1S 132
#define P0S 68
__global__ __launch_bounds__(512) void gemm_pair_kernel(
    const u32* __restrict__ g1_in, const u32* __restrict__ g1_Wp,
    const float* __restrict__ g1_bih, const float* __restrict__ g1_bhh,
    f16* __restrict__ g1_xg, int g1_t0, int g1_on,
    const float* __restrict__ g0_x, const u32* __restrict__ g0_Wp,
    const float* __restrict__ g0_bih, const float* __restrict__ g0_bhh,
    f16* __restrict__ g0_xg, int g0_t0, int g0_on) {
  __shared__ __align__(16) u32 panel[64 * P1S];
  const int tid = threadIdx.x;
  const int blk = blockIdx.x;
  const int lane = tid & 63;
  const int w = tid >> 6;
  const int lrow = lane & 15;
  const int lk = lane >> 4;

  if (blk < 128) {
    if (!g1_on) return;
    const int b = blk;
    {
      const uint4* src = (const uint4*)(g1_in + ((size_t)b * NS + g1_t0) * 128);
      const int t = tid >> 3, cc = tid & 7;
#pragma unroll
      for (int q = 0; q < 4; ++q) {
        uint4 v = src[t * 32 + cc * 4 + q];
        *(uint4*)&panel[t * P1S + cc * 16 + q * 4] = v;
      }
    }
    float bs[8];
#pragma unroll
    for (int n = 0; n < 8; ++n) {
      const int r = w * 128 + n * 16 + lrow;
      bs[n] = g1_bih[r] + g1_bhh[r];
    }
    __syncthreads();
    f32x4 acc[4][8] = {};
#pragma unroll 1
    for (int kc = 0; kc < 8; ++kc) {
      uint4 af[4];
#pragma unroll
      for (int m = 0; m < 4; ++m)
        af[m] = *(const uint4*)&panel[(m * 16 + lrow) * P1S + kc * 16 + lk * 4];
#pragma unroll
      for (int n = 0; n < 8; ++n) {
        const int r = w * 128 + n * 16 + lrow;
        uint4 bf = *(const uint4*)(g1_Wp + (size_t)r * 128 + kc * 16 + lk * 4);
#pragma unroll
        for (int m = 0; m < 4; ++m)
          acc[m][n] = __builtin_amdgcn_mfma_f32_16x16x32_f16(
              __builtin_bit_cast(f16x8, af[m]), __builtin_bit_cast(f16x8, bf),
              acc[m][n], 0, 0, 0);
      }
    }
#pragma unroll
    for (int m = 0; m < 4; ++m)
#pragma unroll
      for (int n = 0; n < 8; ++n) {
        const int r = w * 128 + n * 16 + lrow;
#pragma unroll
        for (int j = 0; j < 4; ++j) {
          const int t = m * 16 + lk * 4 + j;
          g1_xg[((size_t)b * CH + t) * 1024 + r] = (f16)(acc[m][n][j] + bs[n]);
        }
      }
  } else {
    if (!g0_on) return;
    const int b = blk - 128;
    {
      const float4* src = (const float4*)(g0_x + ((size_t)b * NS + g0_t0) * NV);
      const int t = tid >> 3, cc = tid & 7;
      float4 v0 = src[t * 32 + cc * 4 + 0];
      float4 v1 = src[t * 32 + cc * 4 + 1];
      float4 v2 = src[t * 32 + cc * 4 + 2];
      float4 v3 = src[t * 32 + cc * 4 + 3];
      *(uint4*)&panel[t * P0S + cc * 8 + 0] =
          uint4{pkz(v0.x, v0.y), pkz(v0.z, v0.w), pkz(v1.x, v1.y), pkz(v1.z, v1.w)};
      *(uint4*)&panel[t * P0S + cc * 8 + 4] =
          uint4{pkz(v2.x, v2.y), pkz(v2.z, v2.w), pkz(v3.x, v3.y), pkz(v3.z, v3.w)};
    }
    float bs[8];
#pragma unroll
    for (int n = 0; n < 8; ++n) {
      const int r = w * 128 + n * 16 + lrow;
      bs[n] = g0_bih[r] + g0_bhh[r];
    }
    __syncthreads();
    f32x4 acc[4][8] = {};
#pragma unroll 1
    for (int kc = 0; kc < 4; ++kc) {
      uint4 af[4];
#pragma unroll
      for (int m = 0; m < 4; ++m)
        af[m] = *(const uint4*)&panel[(m * 16 + lrow) * P0S + kc * 16 + lk * 4];
#pragma unroll
      for (int n = 0; n < 8; ++n) {
        const int r = w * 128 + n * 16 + lrow;
        uint4 bf = *(const uint4*)(g0_Wp + (size_t)r * 64 + kc * 16 + lk * 4);
#pragma unroll
        for (int m = 0; m < 4; ++m)
          acc[m][n] = __builtin_amdgcn_mfma_f32_16x16x32_f16(
              __builtin_bit_cast(f16x8, af[m]), __builtin_bit_cast(f16x8, bf),
              acc[m][n], 0, 0, 0);
      }
    }
#pragma unroll
    for (int m = 0; m < 4; ++m)
#pragma unroll
      for (int n = 0; n < 8; ++n) {
        const int r = w * 128 + n * 16 + lrow;
#pragma unroll
        for (int j = 0; j < 4; ++j) {
          const int t = m * 16 + lk * 4 + j;
          g0_xg[((size_t)b * CH + t) * 1024 + r] = (f16)(acc[m][n][j] + bs[n]);
        }
      }
  }
}

// ---------------------------------------------------------------------------
// scan pair — r19 body (best measured, 169us) + TWO latency reorders:
//  1. xg double-buffer: xg comes from L3/HBM (written on other XCDs -> L2
//     miss, ~500-900cyc). r19 loaded it at step top and consumed mid-step
//     (exposed stall). Now step t loads step t+1's xg; consumption uses the
//     previous iteration's registers -> full-step latency cover.
//  2. h-store deferred to after the barrier (next step top) -> its ack drains
//     one barrier later, hidden under a full step.
// Everything else identical: 512t, p=tid&1, u=tid>>1; 24 pin4v + 8 LDS weight
// frags/row; h k=0..15 via uniform DS broadcast, k=16..31 via readlane.
// ---------------------------------------------------------------------------
__global__ __attribute__((amdgpu_flat_work_group_size(512, 512),
                          amdgpu_waves_per_eu(2, 2)))
void scan_pair_kernel(
    const f16* __restrict__ xgA, const u32* __restrict__ WhhAp,
    u32* __restrict__ slotsA, u32* __restrict__ hseedA, float* __restrict__ carryA,
    int t0A, int firstA, int onA,
    const f16* __restrict__ xgB, const u32* __restrict__ WhhBp,
    u32* __restrict__ slotsB, u32* __restrict__ hseedB, float* __restrict__ carryB,
    int t0B, int firstB, int onB) {
  __shared__ uint4 wL0[8][512];                 // r0-row overflow, tid-indexed
  __shared__ uint4 wL1[8][512];                 // r1-row overflow, tid-indexed
  __shared__ __align__(16) u32 hbuf[2][128];    // h as 256 f16, double-buffered

  const int blk = blockIdx.x;
  const int tid = threadIdx.x;
  const f16* xg; const u32* Whhp; u32* slots; u32* hseed; float* carry;
  int t0, first, b;
  if (blk < 128) {
    if (!onA) return;
    b = blk; xg = xgA; Whhp = WhhAp; slots = slotsA; hseed = hseedA; carry = carryA;
    t0 = t0A; first = firstA;
  } else {
    if (!onB) return;
    b = blk - 128; xg = xgB; Whhp = WhhBp; slots = slotsB; hseed = hseedB; carry = carryB;
    t0 = t0B; first = firstB;
  }
  const int p = tid & 1;
  const int u = tid >> 1;
  const int lane = tid & 63;
  const int r0 = p * 256 + u;   // gate i (p=0) / f (p=1)
  const int r1 = r0 + 512;      // gate g (p=0) / o (p=1)

  uint4 w0r[24], w1r[24];
  {
    const u32* p0 = Whhp + (size_t)r0 * 128;
    const u32* p1 = Whhp + (size_t)r1 * 128;
#pragma unroll
    for (int k = 0; k < 32; ++k) {
      uint4 v0 = *(const uint4*)(p0 + 4 * k);
      uint4 v1 = *(const uint4*)(p1 + 4 * k);
      if (k < 24) { w0r[k] = v0; w1r[k] = v1; }
      else { wL0[k - 24][tid] = v0; wL1[k - 24][tid] = v1; }
    }
  }
#pragma unroll
  for (int k = 0; k < 24; ++k) { pin4v(w0r[k]); pin4v(w1r[k]); }
  float c;
  if (first) {
    if (tid < 128) hbuf[0][tid] = 0u;
    c = 0.f;
  } else {
    if (tid < 128) hbuf[0][tid] = hseed[b * 128 + tid];
    c = carry[b * 256 + u];
  }
  // prime xg double-buffer with step 0
  float xa = (float)xg[((size_t)b * CH + 0) * 1024 + r0];
  float xb = (float)xg[((size_t)b * CH + 0) * 1024 + r1];
  float hprev = 0.f;      // h(t-1) value owned by this thread (p==0 lanes)
  __syncthreads();

#pragma unroll 1
  for (int tl = 0; tl < CH; ++tl) {
    const int cur = tl & 1, nxt = cur ^ 1;

    // deferred h-store from previous step (drain hides under this full step)
    if (tl > 0 && p == 0)
      ((f16*)(slots + ((size_t)b * NS + t0 + tl - 1) * 128))[u] = (f16)hprev;

    // prefetch NEXT step's xg (full step to cover L3/HBM latency)
    float xan = 0.f, xbn = 0.f;
    if (tl + 1 < CH) {
      xan = (float)xg[((size_t)b * CH + tl + 1) * 1024 + r0];
      xbn = (float)xg[((size_t)b * CH + tl + 1) * 1024 + r1];
    }

    // per-lane register copy of h u32s {2*lane, 2*lane+1}
    const uint2 hv = *(const uint2*)&hbuf[cur][2 * lane];

    float a0 = 0.f, a1 = 0.f;
    // k = 0..15: h via uniform-address DS broadcast (DS pipe)
#pragma unroll
    for (int k = 0; k < 16; ++k) {
      uint4 hk = *(const uint4*)&hbuf[cur][4 * k];
      const uint4 wa = w0r[k];
      const uint4 wb = w1r[k];
      a0 = fdot2(wa.x, hk.x, a0); a0 = fdot2(wa.y, hk.y, a0);
      a0 = fdot2(wa.z, hk.z, a0); a0 = fdot2(wa.w, hk.w, a0);
      a1 = fdot2(wb.x, hk.x, a1); a1 = fdot2(wb.y, hk.y, a1);
      a1 = fdot2(wb.z, hk.z, a1); a1 = fdot2(wb.w, hk.w, a1);
    }
    // k = 16..31: h via v_readlane broadcast (VALU pipe)
#pragma unroll
    for (int k = 16; k < 32; ++k) {
      const u32 s0 = (u32)__builtin_amdgcn_readlane((int)hv.x, 2 * k);
      const u32 s1 = (u32)__builtin_amdgcn_readlane((int)hv.y, 2 * k);
      const u32 s2 = (u32)__builtin_amdgcn_readlane((int)hv.x, 2 * k + 1);
      const u32 s3 = (u32)__builtin_amdgcn_readlane((int)hv.y, 2 * k + 1);
      const uint4 wa = (k < 24) ? w0r[k] : wL0[k - 24][tid];
      const uint4 wb = (k < 24) ? w1r[k] : wL1[k - 24][tid];
      a0 = fdot2(wa.x, s0, a0); a0 = fdot2(wa.y, s1, a0);
      a0 = fdot2(wa.z, s2, a0); a0 = fdot2(wa.w, s3, a0);
      a1 = fdot2(wb.x, s0, a1); a1 = fdot2(wb.y, s1, a1);
      a1 = fdot2(wb.z, s2, a1); a1 = fdot2(wb.w, s3, a1);
    }
    a0 += xa; a1 += xb;
    const float px0 = __shfl_xor(a0, 1);   // partner lane: other two gates
    const float px1 = __shfl_xor(a1, 1);
    const float ai = p ? px0 : a0;
    const float ag = p ? px1 : a1;
    const float af = p ? a0 : px0;
    const float ao = p ? a1 : px1;
    const float gi = sigm(ai), gg = tanh_(ag), gf = sigm(af), go = sigm(ao);
    c = gf * c + gi * gg;                  // redundant in both lanes (same value)
    const float h = go * tanh_(c);
    if (p == 0) ((f16*)hbuf[nxt])[u] = (f16)h;
    hprev = h;
    xa = xan; xb = xbn;
    __syncthreads();  // single barrier: h(t) visible for next step
  }
  // final h store + seeds/carries
  if (p == 0)
    ((f16*)(slots + ((size_t)b * NS + t0 + CH - 1) * 128))[u] = (f16)hprev;
  if (tid < 128) hseed[b * 128 + tid] = hbuf[0][tid];  // CH even -> final in [0]
  if (p == 0) carry[b * 256 + u] = c;
}

// ---------------------------------------------------------------------------
// outproj: out = Wout·h1 + b, IN PLACE over d_out slots. Unchanged (r11).
// ---------------------------------------------------------------------------
#define OPS 140
static __device__ __forceinline__ int swzc(int col) { return col + 4 * (col >> 5); }

__global__ __launch_bounds__(1024) void outproj_kernel(
    const float* __restrict__ Wout, const float* __restrict__ bout,
    u32* __restrict__ io) {
  const int bs = blockIdx.x;  // 2048 blocks
  const int b = bs >> 4;
  const int t0 = (bs & 15) * 64;
  const int tid = threadIdx.x;
  const int p = tid & 7;
  const int vq = tid >> 3;

  __shared__ u32 h1L[64 * OPS];
  __shared__ float outL[64 * OPS];

  const u32* src = io + ((size_t)b * NS + t0) * 128;
  uint4 s0 = *(const uint4*)(src + (size_t)tid * 8);
  uint4 s1 = *(const uint4*)(src + (size_t)tid * 8 + 4);

  u32 wo[16];
  const float* pw = Wout + (size_t)vq * NH + p * 32;
#pragma unroll
  for (int k = 0; k < 8; ++k) {
    float4 w4 = *(const float4*)(pw + 4 * k);
    wo[2 * k] = pkh(w4.x, w4.y); wo[2 * k + 1] = pkh(w4.z, w4.w);
  }
  const float bo = bout[vq];

  {
    const int sr = tid >> 4;
    const int sc = (tid & 15) * 8;
    const int base = sr * OPS + swzc(sc);
    *(uint4*)&h1L[base] = s0;
    *(uint4*)&h1L[base + 4] = s1;
  }
  __syncthreads();

#pragma unroll 4
  for (int s = 0; s < 64; ++s) {
    float oa = 0.f;
#pragma unroll
    for (int q = 0; q < 4; ++q) {
      uint4 hq = *(const uint4*)&h1L[s * OPS + swzc(p * 16 + 4 * q)];
      u32 hw[4] = {hq.x, hq.y, hq.z, hq.w};
#pragma unroll
      for (int j = 0; j < 4; ++j) oa = fdot2(wo[4 * q + j], hw[j], oa);
    }
    oa += __shfl_xor(oa, 1);
    oa += __shfl_xor(oa, 2);
    oa += __shfl_xor(oa, 4);
    if (p == 0) outL[s * OPS + swzc(vq)] = oa + bo;
  }
  __syncthreads();

  float* df = (float*)(io + ((size_t)b * NS + t0) * 128);
  {
    const int sr = tid >> 4;
    const int sc = (tid & 15) * 8;
    const int base = sr * OPS + swzc(sc);
    *(float4*)(df + (size_t)tid * 8) = *(float4*)&outL[base];
    *(float4*)(df + (size_t)tid * 8 + 4) = *(float4*)&outL[base + 4];
  }
}

extern "C" void kernel_launch(void* const* d_in, const int* in_sizes, int n_in,
                              void* d_out, int out_size, void* d_ws, size_t ws_size,
                              hipStream_t stream) {
  const float* x    = (const float*)d_in[0];
  const float* Wih0 = (const float*)d_in[1];
  const float* Whh0 = (const float*)d_in[2];
  const float* bih0 = (const float*)d_in[3];
  const float* bhh0 = (const float*)d_in[4];
  const float* Wih1 = (const float*)d_in[5];
  const float* Whh1 = (const float*)d_in[6];
  const float* bih1 = (const float*)d_in[7];
  const float* bhh1 = (const float*)d_in[8];
  const float* Wout = (const float*)d_in[9];
  const float* bout = (const float*)d_in[10];

  // ws (< 38 MiB): xg0 | xg1 | hseed/carry | packed weights
  f16* xg0 = (f16*)d_ws;
  f16* xg1 = (f16*)((char*)d_ws + (16u << 20));
  u32* hseed0 = (u32*)((char*)d_ws + (32u << 20));
  u32* hseed1 = (u32*)((char*)d_ws + (32u << 20) + (64u << 10));
  float* carry0 = (float*)((char*)d_ws + (32u << 20) + (128u << 10));
  float* carry1 = (float*)((char*)d_ws + (32u << 20) + (256u << 10));
  u32* Wih0p = (u32*)((char*)d_ws + (34u << 20));
  u32* Wih1p = (u32*)((char*)d_ws + (35u << 20));
  u32* Whh0p = (u32*)((char*)d_ws + (36u << 20));
  u32* Whh1p = (u32*)((char*)d_ws + (37u << 20));
  u32* slots = (u32*)d_out;  // h0 -> h1 -> f32 out, in place per chunk row

  prepack_kernel<<<448, 1024, 0, stream>>>(Wih0, Wih1, Whh0, Whh1,
                                           Wih0p, Wih1p, Whh0p, Whh1p);

  // prologue: gemm0(0); scan0(0)
  gemm_pair_kernel<<<256, 512, 0, stream>>>(
      nullptr, nullptr, nullptr, nullptr, nullptr, 0, 0,
      x, Wih0p, bih0, bhh0, xg0, 0, 1);
  scan_pair_kernel<<<256, 512, 0, stream>>>(
      nullptr, nullptr, nullptr, nullptr, nullptr, 0, 0, 0,
      xg0, Whh0p, slots, hseed0, carry0, 0, 1, 1);

  // pipeline: {gemm1(s) || gemm0(s+1)}; then {scan1(s) || scan0(s+1)}
  for (int s = 0; s < NCH; ++s) {
    const int g0on = (s + 1 < NCH);
    gemm_pair_kernel<<<256, 512, 0, stream>>>(
        slots, Wih1p, bih1, bhh1, xg1, s * CH, 1,
        x, Wih0p, bih0, bhh0, xg0, (s + 1) * CH, g0on);
    scan_pair_kernel<<<256, 512, 0, stream>>>(
        xg1, Whh1p, slots, hseed1, carry1, s * CH, (s == 0) ? 1 : 0, 1,
        xg0, Whh0p, slots, hseed0, carry0, (s + 1) * CH, 0, g0on);
  }
  outproj_kernel<<<2048, 1024, 0, stream>>>(Wout, bout, slots);
}

// Round 24
// 3190.979 us; speedup vs baseline: 4.0875x; 1.0401x over previous
//
#include <hip/hip_runtime.h>
#include <cstdint>

#define NB 128   // batch
#define NS 1024  // seq len
#define NV 128   // input dim
#define NH 256   // hidden
#define CH 64    // chunk length
#define NCH (NS / CH)

typedef _Float16 f16;
typedef _Float16 h2 __attribute__((ext_vector_type(2)));
typedef _Float16 f16x8 __attribute__((ext_vector_type(8)));
typedef float f32x4 __attribute__((ext_vector_type(4)));
typedef uint32_t u32;

static __device__ __forceinline__ float fdot2(u32 a, u32 b, float c) {
  return __builtin_amdgcn_fdot2(__builtin_bit_cast(h2, a),
                                __builtin_bit_cast(h2, b), c, false);
}
static __device__ __forceinline__ u32 pkh(float a, float b) {  // RTN
  union { h2 h; u32 u; } cv; cv.h = h2{(f16)a, (f16)b}; return cv.u;
}
static __device__ __forceinline__ u32 pkz(float a, float b) {  // RTZ (x only)
  return __builtin_bit_cast(u32, __builtin_amdgcn_cvt_pkrtz(a, b));
}
static __device__ __forceinline__ float sigm(float x) { return 1.f / (1.f + __expf(-x)); }
static __device__ __forceinline__ float tanh_(float x) { return 1.f - 2.f / (__expf(2.f * x) + 1.f); }

static __device__ __forceinline__ void pin4v(uint4& v) {
  asm volatile("" : "+v"(v.x), "+v"(v.y), "+v"(v.z), "+v"(v.w));
}

// ---------------------------------------------------------------------------
// prepack: four weight matrices f32 -> packed f16 pairs, once per call.
// ---------------------------------------------------------------------------
__global__ __launch_bounds__(1024) void prepack_kernel(
    const float* __restrict__ Wih0, const float* __restrict__ Wih1,
    const float* __restrict__ Whh0, const float* __restrict__ Whh1,
    u32* __restrict__ Wih0p, u32* __restrict__ Wih1p,
    u32* __restrict__ Whh0p, u32* __restrict__ Whh1p) {
  const int g = blockIdx.x * 1024 + threadIdx.x;
  const float* src; u32* dst; int off;
  if (g < 65536)       { src = Wih0; dst = Wih0p; off = g; }
  else if (g < 196608) { src = Wih1; dst = Wih1p; off = g - 65536; }
  else if (g < 327680) { src = Whh0; dst = Whh0p; off = g - 196608; }
  else                 { src = Whh1; dst = Whh1p; off = g - 327680; }
  dst[off] = pkh(src[2 * off], src[2 * off + 1]);
}

// ---------------------------------------------------------------------------
// gemm pair, MFMA version — byte-identical to r18..r20 (validated, ~15us).
// ---------------------------------------------------------------------------
#define P1S 132
#define P0S 68
__global__ __launch_bounds__(512) void gemm_pair_kernel(
    const u32* __restrict__ g1_in, const u32* __restrict__ g1_Wp,
    const float* __restrict__ g1_bih, const float* __restrict__ g1_bhh,
    f16* __restrict__ g1_xg, int g1_t0, int g1_on,
    const float* __restrict__ g0_x, const u32* __restrict__ g0_Wp,
    const float* __restrict__ g0_bih, const float* __restrict__ g0_bhh,
    f16* __restrict__ g0_xg, int g0_t0, int g0_on) {
  __shared__ __align__(16) u32 panel[64 * P1S];
  const int tid = threadIdx.x;
  const int blk = blockIdx.x;
  const int lane = tid & 63;
  const int w = tid >> 6;
  const int lrow = lane & 15;
  const int lk = lane >> 4;

  if (blk < 128) {
    if (!g1_on) return;
    const int b = blk;
    {
      const uint4* src = (const uint4*)(g1_in + ((size_t)b * NS + g1_t0) * 128);
      const int t = tid >> 3, cc = tid & 7;
#pragma unroll
      for (int q = 0; q < 4; ++q) {
        uint4 v = src[t * 32 + cc * 4 + q];
        *(uint4*)&panel[t * P1S + cc * 16 + q * 4] = v;
      }
    }
    float bs[8];
#pragma unroll
    for (int n = 0; n < 8; ++n) {
      const int r = w * 128 + n * 16 + lrow;
      bs[n] = g1_bih[r] + g1_bhh[r];
    }
    __syncthreads();
    f32x4 acc[4][8] = {};
#pragma unroll 1
    for (int kc = 0; kc < 8; ++kc) {
      uint4 af[4];
#pragma unroll
      for (int m = 0; m < 4; ++m)
        af[m] = *(const uint4*)&panel[(m * 16 + lrow) * P1S + kc * 16 + lk * 4];
#pragma unroll
      for (int n = 0; n < 8; ++n) {
        const int r = w * 128 + n * 16 + lrow;
        uint4 bf = *(const uint4*)(g1_Wp + (size_t)r * 128 + kc * 16 + lk * 4);
#pragma unroll
        for (int m = 0; m < 4; ++m)
          acc[m][n] = __builtin_amdgcn_mfma_f32_16x16x32_f16(
              __builtin_bit_cast(f16x8, af[m]), __builtin_bit_cast(f16x8, bf),
              acc[m][n], 0, 0, 0);
      }
    }
#pragma unroll
    for (int m = 0; m < 4; ++m)
#pragma unroll
      for (int n = 0; n < 8; ++n) {
        const int r = w * 128 + n * 16 + lrow;
#pragma unroll
        for (int j = 0; j < 4; ++j) {
          const int t = m * 16 + lk * 4 + j;
          g1_xg[((size_t)b * CH + t) * 1024 + r] = (f16)(acc[m][n][j] + bs[n]);
        }
      }
  } else {
    if (!g0_on) return;
    const int b = blk - 128;
    {
      const float4* src = (const float4*)(g0_x + ((size_t)b * NS + g0_t0) * NV);
      const int t = tid >> 3, cc = tid & 7;
      float4 v0 = src[t * 32 + cc * 4 + 0];
      float4 v1 = src[t * 32 + cc * 4 + 1];
      float4 v2 = src[t * 32 + cc * 4 + 2];
      float4 v3 = src[t * 32 + cc * 4 + 3];
      *(uint4*)&panel[t * P0S + cc * 8 + 0] =
          uint4{pkz(v0.x, v0.y), pkz(v0.z, v0.w), pkz(v1.x, v1.y), pkz(v1.z, v1.w)};
      *(uint4*)&panel[t * P0S + cc * 8 + 4] =
          uint4{pkz(v2.x, v2.y), pkz(v2.z, v2.w), pkz(v3.x, v3.y), pkz(v3.z, v3.w)};
    }
    float bs[8];
#pragma unroll
    for (int n = 0; n < 8; ++n) {
      const int r = w * 128 + n * 16 + lrow;
      bs[n] = g0_bih[r] + g0_bhh[r];
    }
    __syncthreads();
    f32x4 acc[4][8] = {};
#pragma unroll 1
    for (int kc = 0; kc < 4; ++kc) {
      uint4 af[4];
#pragma unroll
      for (int m = 0; m < 4; ++m)
        af[m] = *(const uint4*)&panel[(m * 16 + lrow) * P0S + kc * 16 + lk * 4];
#pragma unroll
      for (int n = 0; n < 8; ++n) {
        const int r = w * 128 + n * 16 + lrow;
        uint4 bf = *(const uint4*)(g0_Wp + (size_t)r * 64 + kc * 16 + lk * 4);
#pragma unroll
        for (int m = 0; m < 4; ++m)
          acc[m][n] = __builtin_amdgcn_mfma_f32_16x16x32_f16(
              __builtin_bit_cast(f16x8, af[m]), __builtin_bit_cast(f16x8, bf),
              acc[m][n], 0, 0, 0);
      }
    }
#pragma unroll
    for (int m = 0; m < 4; ++m)
#pragma unroll
      for (int n = 0; n < 8; ++n) {
        const int r = w * 128 + n * 16 + lrow;
#pragma unroll
        for (int j = 0; j < 4; ++j) {
          const int t = m * 16 + lk * 4 + j;
          g0_xg[((size_t)b * CH + t) * 1024 + r] = (f16)(acc[m][n][j] + bs[n]);
        }
      }
  }
}

// ---------------------------------------------------------------------------
// scan pair — r19/r20 body VERBATIM (best verified: 169us, passed post-timing
// re-validation twice). 512t; p=tid&1, u=tid>>1; rows r0=p*256+u, r1=r0+512;
// 24 pin4v + 8 LDS weight frags/row; h k=0..15 via uniform DS broadcast,
// k=16..31 via v_readlane; one shfl_xor gate exchange; ONE barrier/step.
// ---------------------------------------------------------------------------
__global__ __attribute__((amdgpu_flat_work_group_size(512, 512),
                          amdgpu_waves_per_eu(2, 2)))
void scan_pair_kernel(
    const f16* __restrict__ xgA, const u32* __restrict__ WhhAp,
    u32* __restrict__ slotsA, u32* __restrict__ hseedA, float* __restrict__ carryA,
    int t0A, int firstA, int onA,
    const f16* __restrict__ xgB, const u32* __restrict__ WhhBp,
    u32* __restrict__ slotsB, u32* __restrict__ hseedB, float* __restrict__ carryB,
    int t0B, int firstB, int onB) {
  __shared__ uint4 wL0[8][512];                 // r0-row overflow, tid-indexed
  __shared__ uint4 wL1[8][512];                 // r1-row overflow, tid-indexed
  __shared__ __align__(16) u32 hbuf[2][128];    // h as 256 f16, double-buffered

  const int blk = blockIdx.x;
  const int tid = threadIdx.x;
  const f16* xg; const u32* Whhp; u32* slots; u32* hseed; float* carry;
  int t0, first, b;
  if (blk < 128) {
    if (!onA) return;
    b = blk; xg = xgA; Whhp = WhhAp; slots = slotsA; hseed = hseedA; carry = carryA;
    t0 = t0A; first = firstA;
  } else {
    if (!onB) return;
    b = blk - 128; xg = xgB; Whhp = WhhBp; slots = slotsB; hseed = hseedB; carry = carryB;
    t0 = t0B; first = firstB;
  }
  const int p = tid & 1;
  const int u = tid >> 1;
  const int lane = tid & 63;
  const int r0 = p * 256 + u;   // gate i (p=0) / f (p=1)
  const int r1 = r0 + 512;      // gate g (p=0) / o (p=1)

  uint4 w0r[24], w1r[24];
  {
    const u32* p0 = Whhp + (size_t)r0 * 128;
    const u32* p1 = Whhp + (size_t)r1 * 128;
#pragma unroll
    for (int k = 0; k < 32; ++k) {
      uint4 v0 = *(const uint4*)(p0 + 4 * k);
      uint4 v1 = *(const uint4*)(p1 + 4 * k);
      if (k < 24) { w0r[k] = v0; w1r[k] = v1; }
      else { wL0[k - 24][tid] = v0; wL1[k - 24][tid] = v1; }
    }
  }
#pragma unroll
  for (int k = 0; k < 24; ++k) { pin4v(w0r[k]); pin4v(w1r[k]); }
  float c;
  if (first) {
    if (tid < 128) hbuf[0][tid] = 0u;
    c = 0.f;
  } else {
    if (tid < 128) hbuf[0][tid] = hseed[b * 128 + tid];
    c = carry[b * 256 + u];
  }
  __syncthreads();

#pragma unroll 1
  for (int tl = 0; tl < CH; ++tl) {
    const int cur = tl & 1, nxt = cur ^ 1;
    const f16* xp = xg + ((size_t)b * CH + tl) * 1024;
    const float xa = (float)xp[r0];
    const float xb = (float)xp[r1];

    // per-lane register copy of h u32s {2*lane, 2*lane+1}
    const uint2 hv = *(const uint2*)&hbuf[cur][2 * lane];

    float a0 = 0.f, a1 = 0.f;
    // k = 0..15: h via uniform-address DS broadcast (DS pipe)
#pragma unroll
    for (int k = 0; k < 16; ++k) {
      uint4 hk = *(const uint4*)&hbuf[cur][4 * k];
      const uint4 wa = w0r[k];
      const uint4 wb = w1r[k];
      a0 = fdot2(wa.x, hk.x, a0); a0 = fdot2(wa.y, hk.y, a0);
      a0 = fdot2(wa.z, hk.z, a0); a0 = fdot2(wa.w, hk.w, a0);
      a1 = fdot2(wb.x, hk.x, a1); a1 = fdot2(wb.y, hk.y, a1);
      a1 = fdot2(wb.z, hk.z, a1); a1 = fdot2(wb.w, hk.w, a1);
    }
    // k = 16..31: h via v_readlane broadcast (VALU pipe)
#pragma unroll
    for (int k = 16; k < 32; ++k) {
      const u32 s0 = (u32)__builtin_amdgcn_readlane((int)hv.x, 2 * k);
      const u32 s1 = (u32)__builtin_amdgcn_readlane((int)hv.y, 2 * k);
      const u32 s2 = (u32)__builtin_amdgcn_readlane((int)hv.x, 2 * k + 1);
      const u32 s3 = (u32)__builtin_amdgcn_readlane((int)hv.y, 2 * k + 1);
      const uint4 wa = (k < 24) ? w0r[k] : wL0[k - 24][tid];
      const uint4 wb = (k < 24) ? w1r[k] : wL1[k - 24][tid];
      a0 = fdot2(wa.x, s0, a0); a0 = fdot2(wa.y, s1, a0);
      a0 = fdot2(wa.z, s2, a0); a0 = fdot2(wa.w, s3, a0);
      a1 = fdot2(wb.x, s0, a1); a1 = fdot2(wb.y, s1, a1);
      a1 = fdot2(wb.z, s2, a1); a1 = fdot2(wb.w, s3, a1);
    }
    a0 += xa; a1 += xb;
    const float px0 = __shfl_xor(a0, 1);   // partner lane: other two gates
    const float px1 = __shfl_xor(a1, 1);
    const float ai = p ? px0 : a0;
    const float ag = p ? px1 : a1;
    const float af = p ? a0 : px0;
    const float ao = p ? a1 : px1;
    const float gi = sigm(ai), gg = tanh_(ag), gf = sigm(af), go = sigm(ao);
    c = gf * c + gi * gg;                  // redundant in both lanes (same value)
    const float h = go * tanh_(c);
    if (p == 0) {
      ((f16*)hbuf[nxt])[u] = (f16)h;
      ((f16*)(slots + ((size_t)b * NS + t0 + tl) * 128))[u] = (f16)h;
    }
    __syncthreads();  // single barrier: h(t) visible for next step
  }
  if (tid < 128) hseed[b * 128 + tid] = hbuf[0][tid];  // CH even -> final in [0]
  if (p == 0) carry[b * 256 + u] = c;
}

// ---------------------------------------------------------------------------
// outproj: out = Wout·h1 + b, IN PLACE over d_out slots. Unchanged (r11).
// ---------------------------------------------------------------------------
#define OPS 140
static __device__ __forceinline__ int swzc(int col) { return col + 4 * (col >> 5); }

__global__ __launch_bounds__(1024) void outproj_kernel(
    const float* __restrict__ Wout, const float* __restrict__ bout,
    u32* __restrict__ io) {
  const int bs = blockIdx.x;  // 2048 blocks
  const int b = bs >> 4;
  const int t0 = (bs & 15) * 64;
  const int tid = threadIdx.x;
  const int p = tid & 7;
  const int vq = tid >> 3;

  __shared__ u32 h1L[64 * OPS];
  __shared__ float outL[64 * OPS];

  const u32* src = io + ((size_t)b * NS + t0) * 128;
  uint4 s0 = *(const uint4*)(src + (size_t)tid * 8);
  uint4 s1 = *(const uint4*)(src + (size_t)tid * 8 + 4);

  u32 wo[16];
  const float* pw = Wout + (size_t)vq * NH + p * 32;
#pragma unroll
  for (int k = 0; k < 8; ++k) {
    float4 w4 = *(const float4*)(pw + 4 * k);
    wo[2 * k] = pkh(w4.x, w4.y); wo[2 * k + 1] = pkh(w4.z, w4.w);
  }
  const float bo = bout[vq];

  {
    const int sr = tid >> 4;
    const int sc = (tid & 15) * 8;
    const int base = sr * OPS + swzc(sc);
    *(uint4*)&h1L[base] = s0;
    *(uint4*)&h1L[base + 4] = s1;
  }
  __syncthreads();

#pragma unroll 4
  for (int s = 0; s < 64; ++s) {
    float oa = 0.f;
#pragma unroll
    for (int q = 0; q < 4; ++q) {
      uint4 hq = *(const uint4*)&h1L[s * OPS + swzc(p * 16 + 4 * q)];
      u32 hw[4] = {hq.x, hq.y, hq.z, hq.w};
#pragma unroll
      for (int j = 0; j < 4; ++j) oa = fdot2(wo[4 * q + j], hw[j], oa);
    }
    oa += __shfl_xor(oa, 1);
    oa += __shfl_xor(oa, 2);
    oa += __shfl_xor(oa, 4);
    if (p == 0) outL[s * OPS + swzc(vq)] = oa + bo;
  }
  __syncthreads();

  float* df = (float*)(io + ((size_t)b * NS + t0) * 128);
  {
    const int sr = tid >> 4;
    const int sc = (tid & 15) * 8;
    const int base = sr * OPS + swzc(sc);
    *(float4*)(df + (size_t)tid * 8) = *(float4*)&outL[base];
    *(float4*)(df + (size_t)tid * 8 + 4) = *(float4*)&outL[base + 4];
  }
}

extern "C" void kernel_launch(void* const* d_in, const int* in_sizes, int n_in,
                              void* d_out, int out_size, void* d_ws, size_t ws_size,
                              hipStream_t stream) {
  const float* x    = (const float*)d_in[0];
  const float* Wih0 = (const float*)d_in[1];
  const float* Whh0 = (const float*)d_in[2];
  const float* bih0 = (const float*)d_in[3];
  const float* bhh0 = (const float*)d_in[4];
  const float* Wih1 = (const float*)d_in[5];
  const float* Whh1 = (const float*)d_in[6];
  const float* bih1 = (const float*)d_in[7];
  const float* bhh1 = (const float*)d_in[8];
  const float* Wout = (const float*)d_in[9];
  const float* bout = (const float*)d_in[10];

  // ws (< 38 MiB): xg0 | xg1 | hseed/carry | packed weights
  f16* xg0 = (f16*)d_ws;
  f16* xg1 = (f16*)((char*)d_ws + (16u << 20));
  u32* hseed0 = (u32*)((char*)d_ws + (32u << 20));
  u32* hseed1 = (u32*)((char*)d_ws + (32u << 20) + (64u << 10));
  float* carry0 = (float*)((char*)d_ws + (32u << 20) + (128u << 10));
  float* carry1 = (float*)((char*)d_ws + (32u << 20) + (256u << 10));
  u32* Wih0p = (u32*)((char*)d_ws + (34u << 20));
  u32* Wih1p = (u32*)((char*)d_ws + (35u << 20));
  u32* Whh0p = (u32*)((char*)d_ws + (36u << 20));
  u32* Whh1p = (u32*)((char*)d_ws + (37u << 20));
  u32* slots = (u32*)d_out;  // h0 -> h1 -> f32 out, in place per chunk row

  prepack_kernel<<<448, 1024, 0, stream>>>(Wih0, Wih1, Whh0, Whh1,
                                           Wih0p, Wih1p, Whh0p, Whh1p);

  // prologue: gemm0(0); scan0(0)
  gemm_pair_kernel<<<256, 512, 0, stream>>>(
      nullptr, nullptr, nullptr, nullptr, nullptr, 0, 0,
      x, Wih0p, bih0, bhh0, xg0, 0, 1);
  scan_pair_kernel<<<256, 512, 0, stream>>>(
      nullptr, nullptr, nullptr, nullptr, nullptr, 0, 0, 0,
      xg0, Whh0p, slots, hseed0, carry0, 0, 1, 1);

  // pipeline: {gemm1(s) || gemm0(s+1)}; then {scan1(s) || scan0(s+1)}
  for (int s = 0; s < NCH; ++s) {
    const int g0on = (s + 1 < NCH);
    gemm_pair_kernel<<<256, 512, 0, stream>>>(
        slots, Wih1p, bih1, bhh1, xg1, s * CH, 1,
        x, Wih0p, bih0, bhh0, xg0, (s + 1) * CH, g0on);
    scan_pair_kernel<<<256, 512, 0, stream>>>(
        xg1, Whh1p, slots, hseed1, carry1, s * CH, (s == 0) ? 1 : 0, 1,
        xg0, Whh0p, slots, hseed0, carry0, (s + 1) * CH, 0, g0on);
  }
  outproj_kernel<<<2048, 1024, 0, stream>>>(Wout, bout, slots);
}